// Round 5
// baseline (3180.457 us; speedup 1.0000x reference)
//
#include <hip/hip_runtime.h>

// MultiGNN: B=256, A=64 -> 16384 images of 8x15x15
// convs: 8->16 (15->13), 16->32 (13->11), 32->16 (11->9), 16->32 (9->7)
// flatten 32*7*7=1568 -> MLP 128,128,128 -> GCN over 64 agents, E=128
//
// R5: per-SIMD issue balance. R4 showed occupancy 23->53% changed nothing:
// the invariant is the busiest SIMD's FMA instruction stream (19.3k
// cy/image; exec-masked lanes still cost issue). This round: (1) items
// spread across waves (item = wv + 4*lane) so all 4 SIMDs issue equally;
// (2) finer items (co-single everywhere + x-splits with even x0 ->
// float2 reads, static xs indexing) cut the per-SIMD stream to 12.5k
// cy/image (-35%); (3) wa/wb ping-pong weight prefetch across ci pairs.
// Arena 30.2KB, 5 blocks/CU, weights from global (cache-hot).

#define NIMG 16384

// ---------------- LDS arena layout (floats, 1 image) -----------------------
// L0 @0    : 3328 (16ch x 13 x stride16, x XOR-swizzled per row)
// IN @3328 : 2400 (8ch x 15 x stride20)      dead after L0 pass
// L1 @3328 : 4224 (32ch x 11 x stride12)     overlaps dead IN
// L2 @0    : 1728 (16ch x 9 x stride12)      overlaps dead L0
// L3 @1728 : 1568 (flat 32x7x7)              after dead L0 tail
#define ARENA_F 7552
#define OFF_L0    0
#define OFF_IN    3328
#define OFF_L1    3328
#define OFF_L2    0
#define OFF_L3    1728

// ---------------------------------------------------------------------------
// One-time weight transpose: wt[l][r][co] = cw[l][co][r], r = ci*9+ky*3+kx
// ---------------------------------------------------------------------------
__global__ __launch_bounds__(256) void transpose_w(
    const float* __restrict__ c0, const float* __restrict__ c1,
    const float* __restrict__ c2, const float* __restrict__ c3,
    float* __restrict__ w0, float* __restrict__ w1,
    float* __restrict__ w2, float* __restrict__ w3)
{
    int g = blockIdx.x * 256 + threadIdx.x;
    const float* src; float* dst; int CI9, CO, loc;
    if (g < 1152)       { src = c0; dst = w0; CI9 = 72;  CO = 16; loc = g; }
    else if (g < 5760)  { src = c1; dst = w1; CI9 = 144; CO = 32; loc = g - 1152; }
    else if (g < 10368) { src = c2; dst = w2; CI9 = 288; CO = 16; loc = g - 5760; }
    else if (g < 14976) { src = c3; dst = w3; CI9 = 144; CO = 32; loc = g - 10368; }
    else return;
    int r = loc / CO, co = loc - r * CO;
    dst[loc] = src[co * CI9 + r];
}

// ---------------------------------------------------------------------------
// Single-image conv pass, wave-balanced items.
// item = round*256 + wv + 4*lane; decode cog (fastest), seg, y.
// Each item: SLOTS output columns at x0=seg*X0STEP, COW output channels,
// one row, full CI. Reads: NF4 float4 (x0 must be 0 mod 4) or NF2 float2
// (x0 even) starting at x0 -> xs[] statically indexed. IN_SWZ/OUT_SWZ:
// quad XOR swizzle x ^ ((y&3)<<2) (pairs/quads preserved).
// Weights from global ([r][co]), wa/wb ping-pong prefetch per ci-pair.
// ---------------------------------------------------------------------------
template<int CI, int COW, int NCOG, int HO, int WO, int SLOTS, int NSEG,
         int X0STEP, int IN_RS, int IN_PLANE, int OUT_RS, int OUT_PLANE,
         int NF4, int NF2, int IN_SWZ, int OUT_SWZ>
__device__ __forceinline__ void conv1(
    const float* __restrict__ sIn, float* __restrict__ sOut,
    const float* __restrict__ wt, const float* __restrict__ bias, int tid)
{
    constexpr int CO = NCOG * COW;
    constexpr int NITEMS = NCOG * NSEG * HO;
    constexpr int NROUNDS = (NITEMS + 255) / 256;
    constexpr int XN = NF4 ? NF4 * 4 : NF2 * 2;

    const int lane = tid & 63;
    const int wv   = tid >> 6;

#pragma unroll 1
    for (int r = 0; r < NROUNDS; r++) {
        const int item = r * 256 + wv + 4 * lane;
        if (item < NITEMS) {
            const int cog = item % NCOG;
            const int t   = item / NCOG;
            const int seg = t % NSEG;
            const int y   = t / NSEG;
            const int x0  = seg * X0STEP;

            float acc[SLOTS][COW];
#pragma unroll
            for (int c = 0; c < COW; c++) {
                const float b = bias[cog * COW + c];
#pragma unroll
                for (int q = 0; q < SLOTS; q++) acc[q][c] = b;
            }

            const float* __restrict__ ip0 = sIn + y * IN_RS;
            const float* __restrict__ wp0 = wt + cog * COW;

            auto loadW = [&](float (&dst)[9 * COW], int cidx) {
                const float* __restrict__ wp = wp0 + cidx * 9 * CO;
#pragma unroll
                for (int k = 0; k < 9; k++)
#pragma unroll
                    for (int c = 0; c < COW; c++)
                        dst[k * COW + c] = wp[k * CO + c];
            };

            auto bodyF = [&](int cidx, const float (&w)[9 * COW]) {
                const float* __restrict__ ip = ip0 + cidx * IN_PLANE;
#pragma unroll
                for (int ky = 0; ky < 3; ky++) {
                    const float* __restrict__ rp = ip + ky * IN_RS;
                    const int sw = IN_SWZ ? (((y + ky) & 3) << 2) : 0;
                    float xs[XN];
                    if (NF4) {
#pragma unroll
                        for (int j = 0; j < NF4; j++) {
                            float4 v = *(const float4*)(rp + ((x0 + j * 4) ^ sw));
                            xs[j * 4 + 0] = v.x; xs[j * 4 + 1] = v.y;
                            xs[j * 4 + 2] = v.z; xs[j * 4 + 3] = v.w;
                        }
                    } else {
#pragma unroll
                        for (int j = 0; j < NF2; j++) {
                            float2 v = *(const float2*)(rp + ((x0 + j * 2) ^ sw));
                            xs[j * 2 + 0] = v.x; xs[j * 2 + 1] = v.y;
                        }
                    }
#pragma unroll
                    for (int kx = 0; kx < 3; kx++)
#pragma unroll
                        for (int q = 0; q < SLOTS; q++) {
                            const float iv = xs[q + kx];
#pragma unroll
                            for (int c = 0; c < COW; c++)
                                acc[q][c] += iv * w[(ky * 3 + kx) * COW + c];
                        }
                }
            };

            float wa[9 * COW], wb[9 * COW];
            loadW(wa, 0);
#pragma unroll 1
            for (int ci = 0; ci < CI; ci += 2) {
                loadW(wb, ci + 1);
                bodyF(ci, wa);
                if (ci + 2 < CI) loadW(wa, ci + 2);
                bodyF(ci + 1, wb);
            }

            const int swo = OUT_SWZ ? ((y & 3) << 2) : 0;
            float* __restrict__ op = sOut + y * OUT_RS;
#pragma unroll
            for (int q = 0; q < SLOTS; q++) {
                if (x0 + q < WO) {
#pragma unroll
                    for (int c = 0; c < COW; c++)
                        op[(cog * COW + c) * OUT_PLANE + ((x0 + q) ^ swo)] =
                            fmaxf(acc[q][c], 0.0f);
                }
            }
        }
    }
}

__global__ __launch_bounds__(256, 5) void conv_stack3(
    const float* __restrict__ states,
    const float* __restrict__ wt0, const float* __restrict__ cb0,
    const float* __restrict__ wt1, const float* __restrict__ cb1,
    const float* __restrict__ wt2, const float* __restrict__ cb2,
    const float* __restrict__ wt3, const float* __restrict__ cb3,
    float* __restrict__ x0out)
{
    __shared__ float A[ARENA_F];
    const int tid = threadIdx.x;

    // ---- stage input with row re-pad 15 -> stride 20 ----
    const float* gin = states + (size_t)blockIdx.x * 1800;
#pragma unroll
    for (int j = 0; j < 8; j++) {
        int e = tid + j * 256;
        if (e < 1800) {
            int ci = e / 225, rr = e - ci * 225;
            int y = rr / 15, x = rr - y * 15;
            A[OFF_IN + ci * 300 + y * 20 + x] = gin[e];
        }
    }
    __syncthreads();

    // L0: 8->16, 15->13. co-single x row = 208 items, stream 936.
    conv1<8, 1, 16, 13, 13, 13, 1, 0, 20, 300, 16, 208, 4, 0, 0, 1>(
        A + OFF_IN, A + OFF_L0, wt0, cb0, tid);
    __syncthreads();

    // L1: 16->32, 13->11. co-single x row x x-half {0,6} = 704 items,
    // 3 rounds, stream 864. float2 reads, swizzled input.
    conv1<16, 1, 32, 11, 11, 6, 2, 6, 16, 208, 12, 132, 0, 4, 1, 0>(
        A + OFF_L0, A + OFF_L1, wt1, cb1, tid);
    __syncthreads();

    // L2: 32->16, 11->9. co-single x row x x-pair {0,2,4,6,8} = 720 items,
    // 3 rounds, stream 576. float2 reads.
    conv1<32, 1, 16, 9, 9, 2, 5, 2, 12, 132, 12, 108, 0, 2, 0, 0>(
        A + OFF_L1, A + OFF_L2, wt2, cb2, tid);
    __syncthreads();

    // L3: 16->32, 9->7. co-single x row = 224 items, stream 1008. flat out.
    conv1<16, 1, 32, 7, 7, 7, 1, 0, 12, 108, 7, 49, 3, 0, 0, 0>(
        A + OFF_L2, A + OFF_L3, wt3, cb3, tid);
    __syncthreads();

    // coalesced global store (relu already applied in-pass)
    float* gout = x0out + (size_t)blockIdx.x * 1568;
#pragma unroll
    for (int j = 0; j < 2; j++) {
        int i = tid + j * 256;
        if (i < 392)
            *(float4*)(gout + i * 4) = *(const float4*)(A + OFF_L3 + i * 4);
    }
}

// ---------------------------------------------------------------------------
// GEMM: C[M x 128] = A[M x K] @ W[K x 128] (+bias)(+relu); M-tile 64
// ---------------------------------------------------------------------------
template<int K, bool RELU>
__global__ __launch_bounds__(256) void gemm128(
    const float* __restrict__ Am, const float* __restrict__ Wm,
    const float* __restrict__ bias, float* __restrict__ Cm)
{
    __shared__ float As[64 * 36];
    __shared__ float Ws[32 * 128];

    const int tid = threadIdx.x;
    const int m0  = blockIdx.x * 64;
    const int rg  = tid >> 4;
    const int cg  = tid & 15;

    float acc[4][8];
#pragma unroll
    for (int r = 0; r < 4; r++)
#pragma unroll
        for (int c = 0; c < 8; c++) acc[r][c] = 0.0f;

    for (int k0 = 0; k0 < K; k0 += 32) {
        __syncthreads();
#pragma unroll
        for (int it = 0; it < 2; it++) {
            int idx = tid + it * 256;
            int row = idx >> 3;
            int c4  = idx & 7;
            float4 v = *(const float4*)(Am + (size_t)(m0 + row) * K + k0 + c4 * 4);
            *(float4*)(As + row * 36 + c4 * 4) = v;
        }
#pragma unroll
        for (int it = 0; it < 4; it++) {
            int idx = tid + it * 256;
            int kr  = idx >> 5;
            int c4  = idx & 31;
            float4 v = *(const float4*)(Wm + (size_t)(k0 + kr) * 128 + c4 * 4);
            *(float4*)(Ws + kr * 128 + c4 * 4) = v;
        }
        __syncthreads();

#pragma unroll
        for (int kk = 0; kk < 32; kk++) {
            float a0 = As[(rg * 4 + 0) * 36 + kk];
            float a1 = As[(rg * 4 + 1) * 36 + kk];
            float a2 = As[(rg * 4 + 2) * 36 + kk];
            float a3 = As[(rg * 4 + 3) * 36 + kk];
            float4 w0 = *(const float4*)(Ws + kk * 128 + cg * 8);
            float4 w1 = *(const float4*)(Ws + kk * 128 + cg * 8 + 4);
            acc[0][0] += a0 * w0.x; acc[0][1] += a0 * w0.y; acc[0][2] += a0 * w0.z; acc[0][3] += a0 * w0.w;
            acc[0][4] += a0 * w1.x; acc[0][5] += a0 * w1.y; acc[0][6] += a0 * w1.z; acc[0][7] += a0 * w1.w;
            acc[1][0] += a1 * w0.x; acc[1][1] += a1 * w0.y; acc[1][2] += a1 * w0.z; acc[1][3] += a1 * w0.w;
            acc[1][4] += a1 * w1.x; acc[1][5] += a1 * w1.y; acc[1][6] += a1 * w1.z; acc[1][7] += a1 * w1.w;
            acc[2][0] += a2 * w0.x; acc[2][1] += a2 * w0.y; acc[2][2] += a2 * w0.z; acc[2][3] += a2 * w0.w;
            acc[2][4] += a2 * w1.x; acc[2][5] += a2 * w1.y; acc[2][6] += a2 * w1.z; acc[2][7] += a2 * w1.w;
            acc[3][0] += a3 * w0.x; acc[3][1] += a3 * w0.y; acc[3][2] += a3 * w0.z; acc[3][3] += a3 * w0.w;
            acc[3][4] += a3 * w1.x; acc[3][5] += a3 * w1.y; acc[3][6] += a3 * w1.z; acc[3][7] += a3 * w1.w;
        }
    }

#pragma unroll
    for (int r = 0; r < 4; r++) {
        int row = m0 + rg * 4 + r;
        float v[8];
#pragma unroll
        for (int c = 0; c < 8; c++) {
            float x = acc[r][c];
            if (bias) x += bias[cg * 8 + c];
            if (RELU) x = fmaxf(x, 0.0f);
            v[c] = x;
        }
        float* gp = Cm + (size_t)row * 128 + cg * 8;
        *(float4*)(gp)     = make_float4(v[0], v[1], v[2], v[3]);
        *(float4*)(gp + 4) = make_float4(v[4], v[5], v[6], v[7]);
    }
}

// ---------------------------------------------------------------------------
// GCN aggregation: out[b,j] = dinv_j * sum_i (adj[b,i,j]*dinv_i*xw[b,i]) + gb
// ---------------------------------------------------------------------------
__global__ __launch_bounds__(256) void gcn_agg(
    const float* __restrict__ adj, const float* __restrict__ xw,
    const float* __restrict__ gb, float* __restrict__ outp)
{
    __shared__ float sAdj[64 * 64];
    __shared__ float sXW[64 * 128];
    __shared__ float sDinv[64];

    const int b = blockIdx.x;
    const int tid = threadIdx.x;

    const float* ga = adj + (size_t)b * 4096;
#pragma unroll
    for (int it = 0; it < 4; it++) {
        int idx = tid + it * 256;
        *(float4*)(sAdj + idx * 4) = *(const float4*)(ga + idx * 4);
    }
    const float* gx = xw + (size_t)b * 8192;
#pragma unroll
    for (int it = 0; it < 8; it++) {
        int idx = tid + it * 256;
        *(float4*)(sXW + idx * 4) = *(const float4*)(gx + idx * 4);
    }
    __syncthreads();

    if (tid < 64) {
        float d = 0.0f;
        for (int i = 0; i < 64; i++) d += sAdj[i * 64 + tid];
        sDinv[tid] = (d > 0.0f) ? rsqrtf(d) : 0.0f;
    }
    __syncthreads();

#pragma unroll
    for (int it = 0; it < 8; it++) {
        int idx = tid + it * 256;
        int i = idx >> 5;
        float s = sDinv[i];
        float4 v = *(float4*)(sXW + idx * 4);
        v.x *= s; v.y *= s; v.z *= s; v.w *= s;
        *(float4*)(sXW + idx * 4) = v;
    }
    __syncthreads();

    const int j  = tid >> 2;
    const int eb = (tid & 3) * 32;
    float acc[32];
#pragma unroll
    for (int e = 0; e < 32; e++) acc[e] = 0.0f;

    for (int i = 0; i < 64; i++) {
        float wgt = sAdj[i * 64 + j];
        const float* xp = sXW + i * 128 + eb;
#pragma unroll
        for (int e4 = 0; e4 < 8; e4++) {
            float4 v = *(const float4*)(xp + e4 * 4);
            acc[e4 * 4 + 0] += wgt * v.x;
            acc[e4 * 4 + 1] += wgt * v.y;
            acc[e4 * 4 + 2] += wgt * v.z;
            acc[e4 * 4 + 3] += wgt * v.w;
        }
    }

    const float dj = sDinv[j];
    float* go = outp + ((size_t)b * 64 + j) * 128 + eb;
#pragma unroll
    for (int e4 = 0; e4 < 8; e4++) {
        float4 v;
        v.x = acc[e4 * 4 + 0] * dj + gb[eb + e4 * 4 + 0];
        v.y = acc[e4 * 4 + 1] * dj + gb[eb + e4 * 4 + 1];
        v.z = acc[e4 * 4 + 2] * dj + gb[eb + e4 * 4 + 2];
        v.w = acc[e4 * 4 + 3] * dj + gb[eb + e4 * 4 + 3];
        *(float4*)(go + e4 * 4) = v;
    }
}

// ---------------------------------------------------------------------------
extern "C" void kernel_launch(void* const* d_in, const int* in_sizes, int n_in,
                              void* d_out, int out_size, void* d_ws, size_t ws_size,
                              hipStream_t stream)
{
    const float* states = (const float*)d_in[0];
    const float* adj    = (const float*)d_in[1];
    const float* cw0 = (const float*)d_in[2];  const float* cb0 = (const float*)d_in[3];
    const float* cw1 = (const float*)d_in[4];  const float* cb1 = (const float*)d_in[5];
    const float* cw2 = (const float*)d_in[6];  const float* cb2 = (const float*)d_in[7];
    const float* cw3 = (const float*)d_in[8];  const float* cb3 = (const float*)d_in[9];
    const float* mw0 = (const float*)d_in[10]; const float* mb0 = (const float*)d_in[11];
    const float* mw1 = (const float*)d_in[12]; const float* mb1 = (const float*)d_in[13];
    const float* mw2 = (const float*)d_in[14]; const float* mb2 = (const float*)d_in[15];
    const float* gw  = (const float*)d_in[16]; const float* gb  = (const float*)d_in[17];

    float* ws = (float*)d_ws;
    float* X0 = ws;                                   // 16384*1568 floats
    float* Bu = ws + (size_t)25690112;                // 16384*128
    float* Cu = Bu + (size_t)2097152;                 // 16384*128
    float* WT0 = Cu + (size_t)2097152;                // 1152
    float* WT1 = WT0 + 1152;                          // 4608
    float* WT2 = WT1 + 4608;                          // 4608
    float* WT3 = WT2 + 4608;                          // 4608

    float* out = (float*)d_out;

    transpose_w<<<59, 256, 0, stream>>>(cw0, cw1, cw2, cw3, WT0, WT1, WT2, WT3);
    conv_stack3<<<NIMG, 256, 0, stream>>>(states, WT0, cb0, WT1, cb1,
                                          WT2, cb2, WT3, cb3, X0);
    gemm128<1568, true ><<<256, 256, 0, stream>>>(X0, mw0, mb0, Bu);   // H1
    gemm128<128,  true ><<<256, 256, 0, stream>>>(Bu, mw1, mb1, Cu);   // H2
    gemm128<128,  false><<<256, 256, 0, stream>>>(Cu, mw2, mb2, Bu);   // feats
    gemm128<128,  false><<<256, 256, 0, stream>>>(Bu, gw, nullptr, Cu);// xw
    gcn_agg<<<256, 256, 0, stream>>>(adj, Cu, gb, out);
}

// Round 6
// 2109.874 us; speedup vs baseline: 1.5074x; 1.5074x over previous
//
#include <hip/hip_runtime.h>

// MultiGNN: B=256, A=64 -> 16384 images of 8x15x15
// convs: 8->16 (15->13), 16->32 (13->11), 32->16 (11->9), 16->32 (9->7)
// flatten 32*7*7=1568 -> MLP 128,128,128 -> GCN over 64 agents, E=128
//
// R6: lane-packing. Per-SIMD floor = totalMACs/256lanes = 5279 FMA/img;
// R4's co-pair decomposition issued 9648 (41-88% lane packs). Co-single
// items packed into near-full 256-lane rounds cut this to 6264 (-35%).
// R5's scratch disaster (lambda arrays -> 490MB scratch traffic) avoided:
// no lambdas, weights read sequentially from ORIGINAL cw layout
// ([co][ci*9] contiguous) as 9 aligned float4 per ci-quad into a
// statically-indexed wch[9] (compile-time component select). All x0 even
// -> float2/float4 LDS reads, xs[] statically indexed. Arena 30.2KB,
// launch_bounds(256,4) (VGPR cap 128, ~4 blocks/CU).

#define NIMG 16384

// ---------------- LDS arena layout (floats, 1 image) -----------------------
// L0 @0    : 3328 (16ch x 13 x stride16, x XOR-swizzled per row)
// IN @3328 : 2400 (8ch x 15 x stride20)      dead after L0 pass
// L1 @3328 : 4224 (32ch x 11 x stride12)     overlaps dead IN
// L2 @0    : 1728 (16ch x 9 x stride12)      overlaps dead L0
// L3 @1728 : 1568 (flat 32x7x7)              after dead L0 tail
#define ARENA_F 7552
#define OFF_L0    0
#define OFF_IN    3328
#define OFF_L1    3328
#define OFF_L2    0
#define OFF_L3    1728

// ---------------------------------------------------------------------------
// Single-image conv pass, co-single items, packed rounds.
// item = round*256 + tid; decode y (fastest), seg, co (slowest -> lanes in
// a wave span few co values -> weight-load address divergence stays low).
// Each item: SLOTS output columns at x0=seg*X0STEP (x0 always even), one
// output channel co, one row y, full CI reduction.
// Weights: original cw layout, wp = cw + co*CI*9. Per ci-quad: 9 aligned
// float4 loads (36 weights consumed with compile-time indices).
// IN_SWZ/OUT_SWZ: quad XOR swizzle word ^= ((row&3)<<2); float2/float4
// reads are XOR-compatible (bit0/bit1 preserved).
// ---------------------------------------------------------------------------
template<int CI, int NCO, int HO, int WO, int SLOTS, int NSEG, int X0STEP,
         int IN_RS, int IN_PLANE, int OUT_RS, int OUT_PLANE,
         int NF4, int NF2, int IN_SWZ, int OUT_SWZ>
__device__ __forceinline__ void conv1(
    const float* __restrict__ sIn, float* __restrict__ sOut,
    const float* __restrict__ wg, const float* __restrict__ bias, int tid)
{
    constexpr int NITEMS = NCO * NSEG * HO;
    constexpr int NROUNDS = (NITEMS + 255) / 256;
    constexpr int XN = NF4 ? NF4 * 4 : NF2 * 2;
    constexpr int NCQ = CI / 4;

#pragma unroll 1
    for (int r = 0; r < NROUNDS; r++) {
        const int item = r * 256 + tid;
        if (item < NITEMS) {
            const int y   = item % HO;
            const int t   = item / HO;
            const int seg = t % NSEG;
            const int co  = t / NSEG;
            const int x0  = seg * X0STEP;

            float acc[SLOTS];
            {
                const float b = bias[co];
#pragma unroll
                for (int q = 0; q < SLOTS; q++) acc[q] = b;
            }

            const float* __restrict__ wp = wg + co * (CI * 9);

#pragma unroll 1
            for (int cq = 0; cq < NCQ; cq++) {
                float4 wch[9];
#pragma unroll
                for (int c = 0; c < 9; c++)
                    wch[c] = *(const float4*)(wp + cq * 36 + c * 4);

#pragma unroll
                for (int c4 = 0; c4 < 4; c4++) {
                    const float* __restrict__ ip =
                        sIn + (cq * 4 + c4) * IN_PLANE + y * IN_RS;
#pragma unroll
                    for (int ky = 0; ky < 3; ky++) {
                        const float* __restrict__ rp = ip + ky * IN_RS;
                        const int sw = IN_SWZ ? (((y + ky) & 3) << 2) : 0;
                        float xs[XN];
                        if (NF4) {
#pragma unroll
                            for (int j = 0; j < NF4; j++) {
                                float4 v = *(const float4*)(rp + ((x0 + j * 4) ^ sw));
                                xs[j * 4 + 0] = v.x; xs[j * 4 + 1] = v.y;
                                xs[j * 4 + 2] = v.z; xs[j * 4 + 3] = v.w;
                            }
                        } else {
#pragma unroll
                            for (int j = 0; j < NF2; j++) {
                                float2 v = *(const float2*)(rp + ((x0 + j * 2) ^ sw));
                                xs[j * 2 + 0] = v.x; xs[j * 2 + 1] = v.y;
                            }
                        }
#pragma unroll
                        for (int kx = 0; kx < 3; kx++) {
                            constexpr int dummy = 0; (void)dummy;
                            const int wi = c4 * 9 + ky * 3 + kx;   // 0..35, static
                            const float4 w4 = wch[wi >> 2];         // static idx
                            const float wv = ((wi & 3) == 0) ? w4.x :
                                             ((wi & 3) == 1) ? w4.y :
                                             ((wi & 3) == 2) ? w4.z : w4.w;
#pragma unroll
                            for (int q = 0; q < SLOTS; q++)
                                acc[q] += xs[q + kx] * wv;
                        }
                    }
                }
            }

            const int swo = OUT_SWZ ? ((y & 3) << 2) : 0;
            float* __restrict__ op = sOut + co * OUT_PLANE + y * OUT_RS;
#pragma unroll
            for (int q = 0; q < SLOTS; q++)
                if (x0 + q < WO)
                    op[(x0 + q) ^ swo] = fmaxf(acc[q], 0.0f);
        }
    }
}

__global__ __launch_bounds__(256, 4) void conv_stack3(
    const float* __restrict__ states,
    const float* __restrict__ cw0, const float* __restrict__ cb0,
    const float* __restrict__ cw1, const float* __restrict__ cb1,
    const float* __restrict__ cw2, const float* __restrict__ cb2,
    const float* __restrict__ cw3, const float* __restrict__ cb3,
    float* __restrict__ x0out)
{
    __shared__ float A[ARENA_F];
    const int tid = threadIdx.x;

    // ---- stage input with row re-pad 15 -> stride 20 ----
    const float* gin = states + (size_t)blockIdx.x * 1800;
#pragma unroll
    for (int j = 0; j < 8; j++) {
        int e = tid + j * 256;
        if (e < 1800) {
            int ci = e / 225, rr = e - ci * 225;
            int y = rr / 15, x = rr - y * 15;
            A[OFF_IN + ci * 300 + y * 20 + x] = gin[e];
        }
    }
    __syncthreads();

    // L0: 8->16, 15->13. 16co x 13y = 208 items, 1 round, stream 936.
    // out stride16 swizzled.
    conv1<8, 16, 13, 13, 13, 1, 0, 20, 300, 16, 208, 4, 0, 0, 1>(
        A + OFF_IN, A + OFF_L0, cw0, cb0, tid);
    __syncthreads();

    // L1: 16->32, 13->11. 32co x 2xhalf{0,6} x 11y = 704 items, 3 rounds,
    // stream 864/round. float2 reads, swizzled input.
    conv1<16, 32, 11, 11, 6, 2, 6, 16, 208, 12, 132, 0, 4, 1, 0>(
        A + OFF_L0, A + OFF_L1, cw1, cb1, tid);
    __syncthreads();

    // L2: 32->16, 11->9. 16co x 5xpair{0,2,4,6,8} x 9y = 720 items,
    // 3 rounds, stream 576/round. float2 reads.
    conv1<32, 16, 9, 9, 2, 5, 2, 12, 132, 12, 108, 0, 2, 0, 0>(
        A + OFF_L1, A + OFF_L2, cw2, cb2, tid);
    __syncthreads();

    // L3: 16->32, 9->7. 32co x 7y = 224 items, 1 round, stream 1008.
    // flat out (s7/plane49).
    conv1<16, 32, 7, 7, 7, 1, 0, 12, 108, 7, 49, 3, 0, 0, 0>(
        A + OFF_L2, A + OFF_L3, cw3, cb3, tid);
    __syncthreads();

    // coalesced global store (relu already applied in-pass)
    float* gout = x0out + (size_t)blockIdx.x * 1568;
#pragma unroll
    for (int j = 0; j < 2; j++) {
        int i = tid + j * 256;
        if (i < 392)
            *(float4*)(gout + i * 4) = *(const float4*)(A + OFF_L3 + i * 4);
    }
}

// ---------------------------------------------------------------------------
// GEMM: C[M x 128] = A[M x K] @ W[K x 128] (+bias)(+relu); M-tile 64
// ---------------------------------------------------------------------------
template<int K, bool RELU>
__global__ __launch_bounds__(256) void gemm128(
    const float* __restrict__ Am, const float* __restrict__ Wm,
    const float* __restrict__ bias, float* __restrict__ Cm)
{
    __shared__ float As[64 * 36];
    __shared__ float Ws[32 * 128];

    const int tid = threadIdx.x;
    const int m0  = blockIdx.x * 64;
    const int rg  = tid >> 4;
    const int cg  = tid & 15;

    float acc[4][8];
#pragma unroll
    for (int r = 0; r < 4; r++)
#pragma unroll
        for (int c = 0; c < 8; c++) acc[r][c] = 0.0f;

    for (int k0 = 0; k0 < K; k0 += 32) {
        __syncthreads();
#pragma unroll
        for (int it = 0; it < 2; it++) {
            int idx = tid + it * 256;
            int row = idx >> 3;
            int c4  = idx & 7;
            float4 v = *(const float4*)(Am + (size_t)(m0 + row) * K + k0 + c4 * 4);
            *(float4*)(As + row * 36 + c4 * 4) = v;
        }
#pragma unroll
        for (int it = 0; it < 4; it++) {
            int idx = tid + it * 256;
            int kr  = idx >> 5;
            int c4  = idx & 31;
            float4 v = *(const float4*)(Wm + (size_t)(k0 + kr) * 128 + c4 * 4);
            *(float4*)(Ws + kr * 128 + c4 * 4) = v;
        }
        __syncthreads();

#pragma unroll
        for (int kk = 0; kk < 32; kk++) {
            float a0 = As[(rg * 4 + 0) * 36 + kk];
            float a1 = As[(rg * 4 + 1) * 36 + kk];
            float a2 = As[(rg * 4 + 2) * 36 + kk];
            float a3 = As[(rg * 4 + 3) * 36 + kk];
            float4 w0 = *(const float4*)(Ws + kk * 128 + cg * 8);
            float4 w1 = *(const float4*)(Ws + kk * 128 + cg * 8 + 4);
            acc[0][0] += a0 * w0.x; acc[0][1] += a0 * w0.y; acc[0][2] += a0 * w0.z; acc[0][3] += a0 * w0.w;
            acc[0][4] += a0 * w1.x; acc[0][5] += a0 * w1.y; acc[0][6] += a0 * w1.z; acc[0][7] += a0 * w1.w;
            acc[1][0] += a1 * w0.x; acc[1][1] += a1 * w0.y; acc[1][2] += a1 * w0.z; acc[1][3] += a1 * w0.w;
            acc[1][4] += a1 * w1.x; acc[1][5] += a1 * w1.y; acc[1][6] += a1 * w1.z; acc[1][7] += a1 * w1.w;
            acc[2][0] += a2 * w0.x; acc[2][1] += a2 * w0.y; acc[2][2] += a2 * w0.z; acc[2][3] += a2 * w0.w;
            acc[2][4] += a2 * w1.x; acc[2][5] += a2 * w1.y; acc[2][6] += a2 * w1.z; acc[2][7] += a2 * w1.w;
            acc[3][0] += a3 * w0.x; acc[3][1] += a3 * w0.y; acc[3][2] += a3 * w0.z; acc[3][3] += a3 * w0.w;
            acc[3][4] += a3 * w1.x; acc[3][5] += a3 * w1.y; acc[3][6] += a3 * w1.z; acc[3][7] += a3 * w1.w;
        }
    }

#pragma unroll
    for (int r = 0; r < 4; r++) {
        int row = m0 + rg * 4 + r;
        float v[8];
#pragma unroll
        for (int c = 0; c < 8; c++) {
            float x = acc[r][c];
            if (bias) x += bias[cg * 8 + c];
            if (RELU) x = fmaxf(x, 0.0f);
            v[c] = x;
        }
        float* gp = Cm + (size_t)row * 128 + cg * 8;
        *(float4*)(gp)     = make_float4(v[0], v[1], v[2], v[3]);
        *(float4*)(gp + 4) = make_float4(v[4], v[5], v[6], v[7]);
    }
}

// ---------------------------------------------------------------------------
// GCN aggregation: out[b,j] = dinv_j * sum_i (adj[b,i,j]*dinv_i*xw[b,i]) + gb
// ---------------------------------------------------------------------------
__global__ __launch_bounds__(256) void gcn_agg(
    const float* __restrict__ adj, const float* __restrict__ xw,
    const float* __restrict__ gb, float* __restrict__ outp)
{
    __shared__ float sAdj[64 * 64];
    __shared__ float sXW[64 * 128];
    __shared__ float sDinv[64];

    const int b = blockIdx.x;
    const int tid = threadIdx.x;

    const float* ga = adj + (size_t)b * 4096;
#pragma unroll
    for (int it = 0; it < 4; it++) {
        int idx = tid + it * 256;
        *(float4*)(sAdj + idx * 4) = *(const float4*)(ga + idx * 4);
    }
    const float* gx = xw + (size_t)b * 8192;
#pragma unroll
    for (int it = 0; it < 8; it++) {
        int idx = tid + it * 256;
        *(float4*)(sXW + idx * 4) = *(const float4*)(gx + idx * 4);
    }
    __syncthreads();

    if (tid < 64) {
        float d = 0.0f;
        for (int i = 0; i < 64; i++) d += sAdj[i * 64 + tid];
        sDinv[tid] = (d > 0.0f) ? rsqrtf(d) : 0.0f;
    }
    __syncthreads();

#pragma unroll
    for (int it = 0; it < 8; it++) {
        int idx = tid + it * 256;
        int i = idx >> 5;
        float s = sDinv[i];
        float4 v = *(float4*)(sXW + idx * 4);
        v.x *= s; v.y *= s; v.z *= s; v.w *= s;
        *(float4*)(sXW + idx * 4) = v;
    }
    __syncthreads();

    const int j  = tid >> 2;
    const int eb = (tid & 3) * 32;
    float acc[32];
#pragma unroll
    for (int e = 0; e < 32; e++) acc[e] = 0.0f;

    for (int i = 0; i < 64; i++) {
        float wgt = sAdj[i * 64 + j];
        const float* xp = sXW + i * 128 + eb;
#pragma unroll
        for (int e4 = 0; e4 < 8; e4++) {
            float4 v = *(const float4*)(xp + e4 * 4);
            acc[e4 * 4 + 0] += wgt * v.x;
            acc[e4 * 4 + 1] += wgt * v.y;
            acc[e4 * 4 + 2] += wgt * v.z;
            acc[e4 * 4 + 3] += wgt * v.w;
        }
    }

    const float dj = sDinv[j];
    float* go = outp + ((size_t)b * 64 + j) * 128 + eb;
#pragma unroll
    for (int e4 = 0; e4 < 8; e4++) {
        float4 v;
        v.x = acc[e4 * 4 + 0] * dj + gb[eb + e4 * 4 + 0];
        v.y = acc[e4 * 4 + 1] * dj + gb[eb + e4 * 4 + 1];
        v.z = acc[e4 * 4 + 2] * dj + gb[eb + e4 * 4 + 2];
        v.w = acc[e4 * 4 + 3] * dj + gb[eb + e4 * 4 + 3];
        *(float4*)(go + e4 * 4) = v;
    }
}

// ---------------------------------------------------------------------------
extern "C" void kernel_launch(void* const* d_in, const int* in_sizes, int n_in,
                              void* d_out, int out_size, void* d_ws, size_t ws_size,
                              hipStream_t stream)
{
    const float* states = (const float*)d_in[0];
    const float* adj    = (const float*)d_in[1];
    const float* cw0 = (const float*)d_in[2];  const float* cb0 = (const float*)d_in[3];
    const float* cw1 = (const float*)d_in[4];  const float* cb1 = (const float*)d_in[5];
    const float* cw2 = (const float*)d_in[6];  const float* cb2 = (const float*)d_in[7];
    const float* cw3 = (const float*)d_in[8];  const float* cb3 = (const float*)d_in[9];
    const float* mw0 = (const float*)d_in[10]; const float* mb0 = (const float*)d_in[11];
    const float* mw1 = (const float*)d_in[12]; const float* mb1 = (const float*)d_in[13];
    const float* mw2 = (const float*)d_in[14]; const float* mb2 = (const float*)d_in[15];
    const float* gw  = (const float*)d_in[16]; const float* gb  = (const float*)d_in[17];

    float* ws = (float*)d_ws;
    float* X0 = ws;                                   // 16384*1568 floats
    float* Bu = ws + (size_t)25690112;                // 16384*128
    float* Cu = Bu + (size_t)2097152;                 // 16384*128

    float* out = (float*)d_out;

    conv_stack3<<<NIMG, 256, 0, stream>>>(states, cw0, cb0, cw1, cb1,
                                          cw2, cb2, cw3, cb3, X0);
    gemm128<1568, true ><<<256, 256, 0, stream>>>(X0, mw0, mb0, Bu);   // H1
    gemm128<128,  true ><<<256, 256, 0, stream>>>(Bu, mw1, mb1, Cu);   // H2
    gemm128<128,  false><<<256, 256, 0, stream>>>(Cu, mw2, mb2, Bu);   // feats
    gemm128<128,  false><<<256, 256, 0, stream>>>(Bu, gw, nullptr, Cu);// xw
    gcn_agg<<<256, 256, 0, stream>>>(adj, Cu, gb, out);
}

// Round 7
// 1066.455 us; speedup vs baseline: 2.9823x; 1.9784x over previous
//
#include <hip/hip_runtime.h>

// MultiGNN: B=256, A=64 -> 16384 images of 8x15x15
// convs: 8->16 (15->13), 16->32 (13->11), 32->16 (11->9), 16->32 (9->7)
// flatten 32*7*7=1568 -> MLP 128,128,128 -> GCN over 64 agents, E=128
//
// R7 = R1 (proven 815us: 2 img/block, COW=4, b128 reads, L0 XOR swizzle)
// + per-block/per-pass WAVE ROTATION. Model (closes on all R0-R6 data):
// conv time = max(busiest-SIMD VALU issue, LDS-pipe cycles). R1 is
// issue-bound with SIMD0 carrying 16.4k FMA-instrs/block vs 13.4k avg
// (wave 3 idle every pass). Rotating the item->lane map per block+pass
// ((tid + 64*(rot+pass)) & 255) spreads the idle wave across SIMDs ->
// per-SIMD ~= total/4. R6's co-single (5.8e8 bank conflicts, LDS-bound,
// 1952us) and R5's lambda-scratch (490MB spill) are both reverted.

#define NIMG 16384

// ---------------- LDS arena layout (floats) --------------------------------
// L0OUT @0     : 2 x 3328  (16ch x 13 x stride16, x XOR-swizzled per row)
// IN    @6656  : 2 x 2400  (8ch x 15 x stride20)
// L1OUT @6656  : 2 x 4224  (32ch x 11 x stride12)   (IN dead after L0 pass)
// L2OUT @0     : 2 x 1728  (16ch x 9 x stride12)    (L0 dead after L1 pass)
// L3OUT @3456  : 2 x 1568  (flat 32x7x7)
// L3PART@6592  : 2 x 1568                           (L1 dead after L2 pass)
#define ARENA_F 15104
#define OFF_L0    0
#define OFF_IN    6656
#define OFF_L1    6656
#define OFF_L2    0
#define OFF_L3    3456
#define OFF_L3P   6592

// ---------------------------------------------------------------------------
// One-time weight transpose: wt[l][r][co] = cw[l][co][r], r = ci*9+ky*3+kx
// ---------------------------------------------------------------------------
__global__ __launch_bounds__(256) void transpose_w(
    const float* __restrict__ c0, const float* __restrict__ c1,
    const float* __restrict__ c2, const float* __restrict__ c3,
    float* __restrict__ w0, float* __restrict__ w1,
    float* __restrict__ w2, float* __restrict__ w3)
{
    int g = blockIdx.x * 256 + threadIdx.x;
    const float* src; float* dst; int CI9, CO, loc;
    if (g < 1152)       { src = c0; dst = w0; CI9 = 72;  CO = 16; loc = g; }
    else if (g < 5760)  { src = c1; dst = w1; CI9 = 144; CO = 32; loc = g - 1152; }
    else if (g < 10368) { src = c2; dst = w2; CI9 = 288; CO = 16; loc = g - 5760; }
    else if (g < 14976) { src = c3; dst = w3; CI9 = 144; CO = 32; loc = g - 10368; }
    else return;
    int r = loc / CO, co = loc - r * CO;
    dst[loc] = src[co * CI9 + r];
}

// ---------------------------------------------------------------------------
// Generic row-conv pass (R1 structure, COW=4).
// item = cog + NCOG*(chunk + NCHUNK*(y + HO*(half + NSPLIT*img)))
// item index comes in pre-rotated (wave rotation done by caller).
// SLOTS output positions per item starting at x0 = chunk*X0STEP.
// Per (ci,ky): NREAD4 float4 LDS reads cover the input row window, reused
// across kx. IN_SWZ/OUT_SWZ: rows stored with x ^ ((y&3)<<2) (quad-
// preserving XOR -> float4 loads still x-contiguous).
// NSPLIT==2: half0 -> sOut0 (bias-init), half1 -> sOutP (zero-init), no
// relu (combined later). NSPLIT==1: bias + relu here.
// ---------------------------------------------------------------------------
template<int CI_SUB, int CO, int HO, int WO, int SLOTS, int X0STEP, int NCHUNK,
         int NSPLIT, int IN_RS, int IN_PLANE, int IN_IMG,
         int OUT_RS, int OUT_PLANE, int OUT_IMG, int NREAD4,
         int IN_SWZ, int OUT_SWZ>
__device__ __forceinline__ void conv_row(
    const float* __restrict__ sIn, float* __restrict__ sOut0,
    float* __restrict__ sOutP, const float* __restrict__ wt,
    const float* __restrict__ bias, int item)
{
    constexpr int NCOG = CO / 4;
    constexpr int NITEMS = NCOG * NCHUNK * HO * NSPLIT * 2;
    static_assert(NITEMS <= 256, "single pass");
    if (item >= NITEMS) return;

    const int cog = item % NCOG;          item /= NCOG;
    const int chunk = item % NCHUNK;      item /= NCHUNK;
    const int y = item % HO;              item /= HO;
    const int half = item % NSPLIT;       item /= NSPLIT;
    const int img = item;
    const int x0 = chunk * X0STEP;
    const int ci0 = half * CI_SUB;

    float* __restrict__ sOut = (half == 0) ? sOut0 : sOutP;

    float acc[SLOTS][4];
    if (half == 0) {
        const float4 bv = *(const float4*)(bias + cog * 4);
#pragma unroll
        for (int q = 0; q < SLOTS; q++) {
            acc[q][0] = bv.x; acc[q][1] = bv.y; acc[q][2] = bv.z; acc[q][3] = bv.w;
        }
    } else {
#pragma unroll
        for (int q = 0; q < SLOTS; q++)
            acc[q][0] = acc[q][1] = acc[q][2] = acc[q][3] = 0.0f;
    }

    const float* __restrict__ inBase = sIn + img * IN_IMG + y * IN_RS;
    const float* __restrict__ wBase  = wt + cog * 4;

#pragma unroll 2
    for (int ci = 0; ci < CI_SUB; ci++) {
        const float* __restrict__ ip = inBase + (ci0 + ci) * IN_PLANE;
        const float* __restrict__ wp = wBase + (ci0 + ci) * 9 * CO;
#pragma unroll
        for (int ky = 0; ky < 3; ky++) {
            union { float4 v4[NREAD4]; float xs[NREAD4 * 4]; } xv;
            const float* __restrict__ rp = ip + ky * IN_RS;
            const int sw = IN_SWZ ? (((y + ky) & 3) << 2) : 0;
#pragma unroll
            for (int j = 0; j < NREAD4; j++)
                xv.v4[j] = *(const float4*)(rp + ((x0 + j * 4) ^ sw));
            float4 w[3];
#pragma unroll
            for (int kx = 0; kx < 3; kx++)
                w[kx] = *(const float4*)(wp + (ky * 3 + kx) * CO);
#pragma unroll
            for (int kx = 0; kx < 3; kx++) {
#pragma unroll
                for (int q = 0; q < SLOTS; q++) {
                    const float iv = xv.xs[q + kx];
                    acc[q][0] += iv * w[kx].x; acc[q][1] += iv * w[kx].y;
                    acc[q][2] += iv * w[kx].z; acc[q][3] += iv * w[kx].w;
                }
            }
        }
    }

    const int swo = OUT_SWZ ? ((y & 3) << 2) : 0;
    float* __restrict__ op = sOut + img * OUT_IMG + y * OUT_RS;
#pragma unroll
    for (int q = 0; q < SLOTS; q++) {
        if (x0 + q >= WO) break;
#pragma unroll
        for (int cc = 0; cc < 4; cc++) {
            float v = acc[q][cc];
            if (NSPLIT == 1) v = fmaxf(v, 0.0f);
            op[(cog * 4 + cc) * OUT_PLANE + ((x0 + q) ^ swo)] = v;
        }
    }
}

__global__ __launch_bounds__(256, 2) void conv_stack3(
    const float* __restrict__ states,
    const float* __restrict__ wt0, const float* __restrict__ cb0,
    const float* __restrict__ wt1, const float* __restrict__ cb1,
    const float* __restrict__ wt2, const float* __restrict__ cb2,
    const float* __restrict__ wt3, const float* __restrict__ cb3,
    float* __restrict__ x0out)
{
    __shared__ float A[ARENA_F];
    const int tid = threadIdx.x;

    // wave rotation: de-correlate which SIMDs carry the partial/idle waves,
    // per block (XOR-fold so same-CU blocks differ) and per pass.
    const unsigned bx = blockIdx.x;
    const int rot = (int)((bx ^ (bx >> 2) ^ (bx >> 5)) & 3u) << 6;
    const int t0 = (tid + rot) & 255;
    const int t1 = (tid + rot + 64) & 255;
    const int t2 = (tid + rot + 128) & 255;
    const int t3 = (tid + rot + 192) & 255;

    // ---- stage input with row re-pad 15 -> stride 20 ----
    const float* gin = states + (size_t)blockIdx.x * 3600;
    for (int e = tid; e < 3600; e += 256) {
        int img = e / 1800, r = e - img * 1800;
        int ci = r / 225;  r -= ci * 225;
        int y = r / 15, x = r - y * 15;
        A[OFF_IN + img * 2400 + ci * 300 + y * 20 + x] = gin[e];
    }
    __syncthreads();

    // L0: 8->16, 15->13. 2 chunks (x0=0,8), SLOTS=8. out rs16 swizzled.
    conv_row<8, 16, 13, 13, 8, 8, 2, 1, 20, 300, 2400, 16, 208, 3328, 3, 0, 1>(
        A + OFF_IN, A + OFF_L0, A + OFF_L0, wt0, cb0, t0);
    __syncthreads();

    // L1: 16->32, 13->11. full row SLOTS=11. in rs16 swizzled, out rs12.
    conv_row<16, 32, 11, 11, 11, 0, 1, 1, 16, 208, 3328, 12, 132, 4224, 4, 1, 0>(
        A + OFF_L0, A + OFF_L1, A + OFF_L1, wt1, cb1, t1);
    __syncthreads();

    // L2: 32->16, 11->9. aligned x-chunks (x0=0/4, SLOTS=5, col 4 dup'd,
    // same value both writers). Full ci per item -> relu fused, no combine.
    conv_row<32, 16, 9, 9, 5, 4, 2, 1, 12, 132, 4224, 12, 108, 1728, 2, 0, 0>(
        A + OFF_L1, A + OFF_L2, A + OFF_L2, wt2, cb2, t2);
    __syncthreads();

    // L3: 16->32, 9->7. ci-split x2, SLOTS=7, flat out (stride7/plane49)
    conv_row<8, 32, 7, 7, 7, 0, 1, 2, 12, 108, 1728, 7, 49, 1568, 3, 0, 0>(
        A + OFF_L2, A + OFF_L3, A + OFF_L3P, wt3, cb3, t3);
    __syncthreads();

    // combine + relu + coalesced global store (flat [img][32*7*7])
    float* gout = x0out + (size_t)blockIdx.x * 3136;
    for (int i = tid; i < 3136; i += 256) {
        float v = A[OFF_L3 + i] + A[OFF_L3P + i];
        gout[i] = fmaxf(v, 0.0f);
    }
}

// ---------------------------------------------------------------------------
// GEMM: C[M x 128] = A[M x K] @ W[K x 128] (+bias)(+relu); M-tile 64
// ---------------------------------------------------------------------------
template<int K, bool RELU>
__global__ __launch_bounds__(256) void gemm128(
    const float* __restrict__ Am, const float* __restrict__ Wm,
    const float* __restrict__ bias, float* __restrict__ Cm)
{
    __shared__ float As[64 * 36];
    __shared__ float Ws[32 * 128];

    const int tid = threadIdx.x;
    const int m0  = blockIdx.x * 64;
    const int rg  = tid >> 4;
    const int cg  = tid & 15;

    float acc[4][8];
#pragma unroll
    for (int r = 0; r < 4; r++)
#pragma unroll
        for (int c = 0; c < 8; c++) acc[r][c] = 0.0f;

    for (int k0 = 0; k0 < K; k0 += 32) {
        __syncthreads();
#pragma unroll
        for (int it = 0; it < 2; it++) {
            int idx = tid + it * 256;
            int row = idx >> 3;
            int c4  = idx & 7;
            float4 v = *(const float4*)(Am + (size_t)(m0 + row) * K + k0 + c4 * 4);
            *(float4*)(As + row * 36 + c4 * 4) = v;
        }
#pragma unroll
        for (int it = 0; it < 4; it++) {
            int idx = tid + it * 256;
            int kr  = idx >> 5;
            int c4  = idx & 31;
            float4 v = *(const float4*)(Wm + (size_t)(k0 + kr) * 128 + c4 * 4);
            *(float4*)(Ws + kr * 128 + c4 * 4) = v;
        }
        __syncthreads();

#pragma unroll
        for (int kk = 0; kk < 32; kk++) {
            float a0 = As[(rg * 4 + 0) * 36 + kk];
            float a1 = As[(rg * 4 + 1) * 36 + kk];
            float a2 = As[(rg * 4 + 2) * 36 + kk];
            float a3 = As[(rg * 4 + 3) * 36 + kk];
            float4 w0 = *(const float4*)(Ws + kk * 128 + cg * 8);
            float4 w1 = *(const float4*)(Ws + kk * 128 + cg * 8 + 4);
            acc[0][0] += a0 * w0.x; acc[0][1] += a0 * w0.y; acc[0][2] += a0 * w0.z; acc[0][3] += a0 * w0.w;
            acc[0][4] += a0 * w1.x; acc[0][5] += a0 * w1.y; acc[0][6] += a0 * w1.z; acc[0][7] += a0 * w1.w;
            acc[1][0] += a1 * w0.x; acc[1][1] += a1 * w0.y; acc[1][2] += a1 * w0.z; acc[1][3] += a1 * w0.w;
            acc[1][4] += a1 * w1.x; acc[1][5] += a1 * w1.y; acc[1][6] += a1 * w1.z; acc[1][7] += a1 * w1.w;
            acc[2][0] += a2 * w0.x; acc[2][1] += a2 * w0.y; acc[2][2] += a2 * w0.z; acc[2][3] += a2 * w0.w;
            acc[2][4] += a2 * w1.x; acc[2][5] += a2 * w1.y; acc[2][6] += a2 * w1.z; acc[2][7] += a2 * w1.w;
            acc[3][0] += a3 * w0.x; acc[3][1] += a3 * w0.y; acc[3][2] += a3 * w0.z; acc[3][3] += a3 * w0.w;
            acc[3][4] += a3 * w1.x; acc[3][5] += a3 * w1.y; acc[3][6] += a3 * w1.z; acc[3][7] += a3 * w1.w;
        }
    }

#pragma unroll
    for (int r = 0; r < 4; r++) {
        int row = m0 + rg * 4 + r;
        float v[8];
#pragma unroll
        for (int c = 0; c < 8; c++) {
            float x = acc[r][c];
            if (bias) x += bias[cg * 8 + c];
            if (RELU) x = fmaxf(x, 0.0f);
            v[c] = x;
        }
        float* gp = Cm + (size_t)row * 128 + cg * 8;
        *(float4*)(gp)     = make_float4(v[0], v[1], v[2], v[3]);
        *(float4*)(gp + 4) = make_float4(v[4], v[5], v[6], v[7]);
    }
}

// ---------------------------------------------------------------------------
// GCN aggregation: out[b,j] = dinv_j * sum_i (adj[b,i,j]*dinv_i*xw[b,i]) + gb
// ---------------------------------------------------------------------------
__global__ __launch_bounds__(256) void gcn_agg(
    const float* __restrict__ adj, const float* __restrict__ xw,
    const float* __restrict__ gb, float* __restrict__ outp)
{
    __shared__ float sAdj[64 * 64];
    __shared__ float sXW[64 * 128];
    __shared__ float sDinv[64];

    const int b = blockIdx.x;
    const int tid = threadIdx.x;

    const float* ga = adj + (size_t)b * 4096;
#pragma unroll
    for (int it = 0; it < 4; it++) {
        int idx = tid + it * 256;
        *(float4*)(sAdj + idx * 4) = *(const float4*)(ga + idx * 4);
    }
    const float* gx = xw + (size_t)b * 8192;
#pragma unroll
    for (int it = 0; it < 8; it++) {
        int idx = tid + it * 256;
        *(float4*)(sXW + idx * 4) = *(const float4*)(gx + idx * 4);
    }
    __syncthreads();

    if (tid < 64) {
        float d = 0.0f;
        for (int i = 0; i < 64; i++) d += sAdj[i * 64 + tid];
        sDinv[tid] = (d > 0.0f) ? rsqrtf(d) : 0.0f;
    }
    __syncthreads();

#pragma unroll
    for (int it = 0; it < 8; it++) {
        int idx = tid + it * 256;
        int i = idx >> 5;
        float s = sDinv[i];
        float4 v = *(float4*)(sXW + idx * 4);
        v.x *= s; v.y *= s; v.z *= s; v.w *= s;
        *(float4*)(sXW + idx * 4) = v;
    }
    __syncthreads();

    const int j  = tid >> 2;
    const int eb = (tid & 3) * 32;
    float acc[32];
#pragma unroll
    for (int e = 0; e < 32; e++) acc[e] = 0.0f;

    for (int i = 0; i < 64; i++) {
        float wgt = sAdj[i * 64 + j];
        const float* xp = sXW + i * 128 + eb;
#pragma unroll
        for (int e4 = 0; e4 < 8; e4++) {
            float4 v = *(const float4*)(xp + e4 * 4);
            acc[e4 * 4 + 0] += wgt * v.x;
            acc[e4 * 4 + 1] += wgt * v.y;
            acc[e4 * 4 + 2] += wgt * v.z;
            acc[e4 * 4 + 3] += wgt * v.w;
        }
    }

    const float dj = sDinv[j];
    float* go = outp + ((size_t)b * 64 + j) * 128 + eb;
#pragma unroll
    for (int e4 = 0; e4 < 8; e4++) {
        float4 v;
        v.x = acc[e4 * 4 + 0] * dj + gb[eb + e4 * 4 + 0];
        v.y = acc[e4 * 4 + 1] * dj + gb[eb + e4 * 4 + 1];
        v.z = acc[e4 * 4 + 2] * dj + gb[eb + e4 * 4 + 2];
        v.w = acc[e4 * 4 + 3] * dj + gb[eb + e4 * 4 + 3];
        *(float4*)(go + e4 * 4) = v;
    }
}

// ---------------------------------------------------------------------------
extern "C" void kernel_launch(void* const* d_in, const int* in_sizes, int n_in,
                              void* d_out, int out_size, void* d_ws, size_t ws_size,
                              hipStream_t stream)
{
    const float* states = (const float*)d_in[0];
    const float* adj    = (const float*)d_in[1];
    const float* cw0 = (const float*)d_in[2];  const float* cb0 = (const float*)d_in[3];
    const float* cw1 = (const float*)d_in[4];  const float* cb1 = (const float*)d_in[5];
    const float* cw2 = (const float*)d_in[6];  const float* cb2 = (const float*)d_in[7];
    const float* cw3 = (const float*)d_in[8];  const float* cb3 = (const float*)d_in[9];
    const float* mw0 = (const float*)d_in[10]; const float* mb0 = (const float*)d_in[11];
    const float* mw1 = (const float*)d_in[12]; const float* mb1 = (const float*)d_in[13];
    const float* mw2 = (const float*)d_in[14]; const float* mb2 = (const float*)d_in[15];
    const float* gw  = (const float*)d_in[16]; const float* gb  = (const float*)d_in[17];

    float* ws = (float*)d_ws;
    float* X0 = ws;                                   // 16384*1568 floats
    float* Bu = ws + (size_t)25690112;                // 16384*128
    float* Cu = Bu + (size_t)2097152;                 // 16384*128
    float* WT0 = Cu + (size_t)2097152;                // 1152
    float* WT1 = WT0 + 1152;                          // 4608
    float* WT2 = WT1 + 4608;                          // 4608
    float* WT3 = WT2 + 4608;                          // 4608

    float* out = (float*)d_out;

    transpose_w<<<59, 256, 0, stream>>>(cw0, cw1, cw2, cw3, WT0, WT1, WT2, WT3);
    conv_stack3<<<NIMG / 2, 256, 0, stream>>>(states, WT0, cb0, WT1, cb1,
                                              WT2, cb2, WT3, cb3, X0);
    gemm128<1568, true ><<<256, 256, 0, stream>>>(X0, mw0, mb0, Bu);   // H1
    gemm128<128,  true ><<<256, 256, 0, stream>>>(Bu, mw1, mb1, Cu);   // H2
    gemm128<128,  false><<<256, 256, 0, stream>>>(Cu, mw2, mb2, Bu);   // feats
    gemm128<128,  false><<<256, 256, 0, stream>>>(Bu, gw, nullptr, Cu);// xw
    gcn_agg<<<256, 256, 0, stream>>>(adj, Cu, gb, out);
}

// Round 8
// 651.623 us; speedup vs baseline: 4.8808x; 1.6366x over previous
//
#include <hip/hip_runtime.h>

// MultiGNN: B=256, A=64 -> 16384 images of 8x15x15
// convs: 8->16 (15->13), 16->32 (13->11), 32->16 (11->9), 16->32 (9->7)
// flatten 32*7*7=1568 -> MLP 128,128,128 -> GCN over 64 agents, E=128
//
// R8: MFMA conv. Eight rounds of scalar-VALU tuning all plateau ~810us
// (2.9x the 282us fp32 vector floor; MfmaUtil 0). Rewrite conv stack as
// implicit GEMM on matrix cores, split-bf16 (hi+lo, 3 MFMAs per product:
// hh+lh+hl, dropping the ~2^-18 al*bl term) for near-fp32 accuracy.
// Activations channels-last bf16 in LDS (hi/lo planes) -> B-fragment =
// one ds_read_b128 (8 consecutive ci). kx folded into MFMA-K where
// contiguous. Weights pre-packed to A-fragment order by wprep kernel.
// 1 image/block, 26.4KB arena -> ~6 blocks/CU.

typedef short short8 __attribute__((ext_vector_type(8)));
typedef float f32x4  __attribute__((ext_vector_type(4)));

__device__ __forceinline__ unsigned short f2bf(float f) {
    unsigned u = __builtin_bit_cast(unsigned, f);
    u = (u + 0x7FFFu + ((u >> 16) & 1u)) >> 16;
    return (unsigned short)u;
}
__device__ __forceinline__ float bf2f(unsigned short h) {
    unsigned u = ((unsigned)h) << 16;
    return __builtin_bit_cast(float, u);
}

// ---------------- LDS arena (bytes) ----------------------------------------
// L0out @0     : 10816 (13x13x16 bf16, hi + lo at +5408)
// IN    @10816 : 7200  (15x15x8  bf16, hi + lo at +3600)   dead after L0
// L1out @10816 : 15488 (11x11x32 bf16, hi + lo at +7744)   overlaps dead IN
// L2out @0     : 5184  (9x9x16   bf16, hi + lo at +2592)   overlaps dead L0out
// ZED   @26304 : 16B of zeros (pad-lane B reads)
#define ZED_OFF 26304
#define ARENA_FLOATS 6592   // 26368 B

// ---------------------------------------------------------------------------
// Weight prep: pack cw[l] ([co][ci][3][3] fp32) into MFMA A-fragments,
// split-bf16. Element offset within a layer:
//   ((c*NM + m)*2 + comp)*512 + lane*8 + j
// lane: row co = m*16 + (lane&15); k = (lane>>4)*8 + j.
// KIND 0 (L0, CI=8):  c=ky;            k: kx=(lane>>4), ci=j; lane>>4==3 pad
// KIND 1 (L1/L3,CI=16): c=ky*2+half;   half0: kx=g>>1, ci=(g&1)*8+j
//                                      half1: kx=2,    ci=(g&1)*8+j; g>=2 pad
// KIND 2 (L2, CI=32): c=ky*3+kx;       ci = g*8+j
// Layer bases (shorts): L0 0, L1 3072, L2 15360, L3 24576; total 36864.
// ---------------------------------------------------------------------------
__global__ __launch_bounds__(256) void wprep(
    const float* __restrict__ cw0, const float* __restrict__ cw1,
    const float* __restrict__ cw2, const float* __restrict__ cw3,
    short* __restrict__ wbuf)
{
    int gidx = blockIdx.x * 256 + threadIdx.x;
    if (gidx >= 36864) return;
    const float* cw; int base, CI, NM, KIND;
    if (gidx < 3072)       { cw = cw0; base = 0;     CI = 8;  NM = 1; KIND = 0; }
    else if (gidx < 15360) { cw = cw1; base = 3072;  CI = 16; NM = 2; KIND = 1; }
    else if (gidx < 24576) { cw = cw2; base = 15360; CI = 32; NM = 1; KIND = 2; }
    else                   { cw = cw3; base = 24576; CI = 16; NM = 2; KIND = 1; }
    int e = gidx - base;
    int j = e & 7, lane = (e >> 3) & 63, rest = e >> 9;
    int comp = rest & 1, cm = rest >> 1;
    int m = cm % NM, c = cm / NM;
    int g = lane >> 4, colr = lane & 15;
    int co = m * 16 + colr;
    int ky, kx, ci; bool pad = false;
    if (KIND == 0)      { ky = c; kx = g; ci = j; pad = (g >= 3); }
    else if (KIND == 1) {
        ky = c >> 1; int half = c & 1;
        if (half == 0) { kx = g >> 1; ci = (g & 1) * 8 + j; }
        else           { kx = 2;      ci = (g & 1) * 8 + j; pad = (g >= 2); }
    } else              { ky = c / 3; kx = c % 3; ci = g * 8 + j; }
    float w = pad ? 0.0f : cw[((co * CI + ci) * 3 + ky) * 3 + kx];
    unsigned short h = f2bf(w);
    wbuf[gidx] = (comp == 0) ? (short)h : (short)f2bf(w - bf2f(h));
}

// ---------------------------------------------------------------------------
// One conv layer on MFMA. D[co][pix] = sum_k W[co][k] * IN[k][pix], k runs
// over (ky,kx,ci) in K=32 chunks, accumulated over chunks into one f32x4
// acc per 16co x 16pix tile. Per chunk: acc = Ah*Bh + Al*Bh + Ah*Bl + acc.
// B fragment: lane reads 16B at a channels-last LDS offset (per-lane voff,
// invalid pad lanes redirected to ZED). Units (Ntile x Mtile) split across
// the 4 waves.
// ---------------------------------------------------------------------------
template<int CI, int CO, int WIN, int WOUT, int POUT, int NM, int NT,
         int KIND, int INOFF, int DIN, int OUTOFF, int DOUT, int GOUT>
__device__ __forceinline__ void mfma_layer(
    float* __restrict__ A, const short* __restrict__ wbuf,
    const float* __restrict__ bias, float* __restrict__ gOut, int tid)
{
    const char* Ac = (const char*)A;
    char* Aw = (char*)A;
    const int wv = tid >> 6, lane = tid & 63;
    const int g = lane >> 4, col = lane & 15;
    constexpr int UNITS = NT * NM;
    constexpr int CPK = (KIND == 0) ? 1 : (KIND == 1) ? 2 : 3;
    constexpr int KB = WIN * CI * 2;          // ky stride (bytes)
    const int u0 = (UNITS * wv) >> 2, u1 = (UNITS * (wv + 1)) >> 2;

#pragma unroll 1
    for (int u = u0; u < u1; ++u) {
        const int n = u / NM, m = u - n * NM;
        const int p = n * 16 + col;
        const bool valid = (p < POUT);
        const int pix = valid ? p : (POUT - 1);
        const int y = pix / WOUT;
        const int x = pix - y * WOUT;
        const int ob = INOFF + (y * WIN + x) * (CI * 2);
        const int vbF = ob + g * 16;
        const int vbH = ob + (g & 1) * 16;
        const bool fOK = (KIND == 0) ? (g < 3) : true;
        const bool hOK = (g < 2);

        f32x4 acc;
        {
            const float4 bv = *(const float4*)(bias + m * 16 + g * 4);
            acc[0] = bv.x; acc[1] = bv.y; acc[2] = bv.z; acc[3] = bv.w;
        }

#pragma unroll
        for (int ky = 0; ky < 3; ++ky) {
#pragma unroll
            for (int cc = 0; cc < CPK; ++cc) {
                const int c = ky * CPK + cc;
                const int koff = ky * KB +
                    ((KIND == 2) ? cc * (CI * 2) : (cc == 1 ? 2 * (CI * 2) : 0));
                const bool okv = (KIND == 0) ? fOK
                               : ((KIND == 1 && cc == 1) ? hOK : true);
                const int vb = (KIND == 1 && cc == 1) ? vbH : vbF;
                const int vH = okv ? (vb + koff) : ZED_OFF;
                const int vL = okv ? (vb + koff + DIN) : ZED_OFF;

                const short8 Ah = *(const short8*)(
                    wbuf + ((c * NM + m) * 2 + 0) * 512 + lane * 8);
                const short8 Al = *(const short8*)(
                    wbuf + ((c * NM + m) * 2 + 1) * 512 + lane * 8);

                const short8 Bh = *(const short8*)(Ac + vH);
                acc = __builtin_amdgcn_mfma_f32_16x16x32_bf16(Ah, Bh, acc, 0, 0, 0);
                acc = __builtin_amdgcn_mfma_f32_16x16x32_bf16(Al, Bh, acc, 0, 0, 0);
                const short8 Bl = *(const short8*)(Ac + vL);
                acc = __builtin_amdgcn_mfma_f32_16x16x32_bf16(Ah, Bl, acc, 0, 0, 0);
            }
        }

        if (GOUT) {
            if (valid) {
                const int co0 = m * 16 + g * 4;
#pragma unroll
                for (int r = 0; r < 4; ++r)
                    gOut[(co0 + r) * POUT + pix] = fmaxf(acc[r], 0.0f);
            }
        } else if (valid) {
            unsigned hh[2], ll[2];
#pragma unroll
            for (int r2 = 0; r2 < 2; ++r2) {
                float v0 = fmaxf(acc[r2 * 2 + 0], 0.0f);
                float v1 = fmaxf(acc[r2 * 2 + 1], 0.0f);
                unsigned short h0 = f2bf(v0), h1 = f2bf(v1);
                unsigned short l0 = f2bf(v0 - bf2f(h0));
                unsigned short l1 = f2bf(v1 - bf2f(h1));
                hh[r2] = (unsigned)h0 | ((unsigned)h1 << 16);
                ll[r2] = (unsigned)l0 | ((unsigned)l1 << 16);
            }
            const int ob2 = OUTOFF + (pix * CO + m * 16 + g * 4) * 2;
            *(uint2*)(Aw + ob2)        = make_uint2(hh[0], hh[1]);
            *(uint2*)(Aw + ob2 + DOUT) = make_uint2(ll[0], ll[1]);
        }
    }
}

__global__ __launch_bounds__(256) void conv_mfma(
    const float* __restrict__ states, const short* __restrict__ wbuf,
    const float* __restrict__ cb0, const float* __restrict__ cb1,
    const float* __restrict__ cb2, const float* __restrict__ cb3,
    float* __restrict__ x0out)
{
    __shared__ float A[ARENA_FLOATS];
    const int tid = threadIdx.x;

    if (tid < 4) A[ZED_OFF / 4 + tid] = 0.0f;

    // stage input: fp32 [8][15][15] -> channels-last bf16 hi/lo @10816
    const float* gin = states + (size_t)blockIdx.x * 1800;
    {
        char* Aw = (char*)A;
#pragma unroll
        for (int it = 0; it < 8; ++it) {
            int e = tid + it * 256;
            if (e < 1800) {
                float f = gin[e];
                int ci = e / 225, p = e - ci * 225;
                unsigned short h = f2bf(f);
                unsigned short l = f2bf(f - bf2f(h));
                int off = 10816 + (p * 8 + ci) * 2;
                *(short*)(Aw + off) = (short)h;
                *(short*)(Aw + off + 3600) = (short)l;
            }
        }
    }
    __syncthreads();

    // L0: 8->16, 15->13, in @10816 d3600, out @0 d5408
    mfma_layer<8, 16, 15, 13, 169, 1, 11, 0, 10816, 3600, 0, 5408, 0>(
        A, wbuf + 0, cb0, nullptr, tid);
    __syncthreads();
    // L1: 16->32, 13->11, in @0 d5408, out @10816 d7744
    mfma_layer<16, 32, 13, 11, 121, 2, 8, 1, 0, 5408, 10816, 7744, 0>(
        A, wbuf + 3072, cb1, nullptr, tid);
    __syncthreads();
    // L2: 32->16, 11->9, in @10816 d7744, out @0 d2592
    mfma_layer<32, 16, 11, 9, 81, 1, 6, 2, 10816, 7744, 0, 2592, 0>(
        A, wbuf + 15360, cb2, nullptr, tid);
    __syncthreads();
    // L3: 16->32, 9->7, in @0 d2592, out -> global fp32 [co*49+pix]
    float* gOut = x0out + (size_t)blockIdx.x * 1568;
    mfma_layer<16, 32, 9, 7, 49, 2, 4, 1, 0, 2592, 0, 0, 1>(
        A, wbuf + 24576, cb3, gOut, tid);
}

// ---------------------------------------------------------------------------
// GEMM: C[M x 128] = A[M x K] @ W[K x 128] (+bias)(+relu); M-tile 64
// ---------------------------------------------------------------------------
template<int K, bool RELU>
__global__ __launch_bounds__(256) void gemm128(
    const float* __restrict__ Am, const float* __restrict__ Wm,
    const float* __restrict__ bias, float* __restrict__ Cm)
{
    __shared__ float As[64 * 36];
    __shared__ float Ws[32 * 128];

    const int tid = threadIdx.x;
    const int m0  = blockIdx.x * 64;
    const int rg  = tid >> 4;
    const int cg  = tid & 15;

    float acc[4][8];
#pragma unroll
    for (int r = 0; r < 4; r++)
#pragma unroll
        for (int c = 0; c < 8; c++) acc[r][c] = 0.0f;

    for (int k0 = 0; k0 < K; k0 += 32) {
        __syncthreads();
#pragma unroll
        for (int it = 0; it < 2; it++) {
            int idx = tid + it * 256;
            int row = idx >> 3;
            int c4  = idx & 7;
            float4 v = *(const float4*)(Am + (size_t)(m0 + row) * K + k0 + c4 * 4);
            *(float4*)(As + row * 36 + c4 * 4) = v;
        }
#pragma unroll
        for (int it = 0; it < 4; it++) {
            int idx = tid + it * 256;
            int kr  = idx >> 5;
            int c4  = idx & 31;
            float4 v = *(const float4*)(Wm + (size_t)(k0 + kr) * 128 + c4 * 4);
            *(float4*)(Ws + kr * 128 + c4 * 4) = v;
        }
        __syncthreads();

#pragma unroll
        for (int kk = 0; kk < 32; kk++) {
            float a0 = As[(rg * 4 + 0) * 36 + kk];
            float a1 = As[(rg * 4 + 1) * 36 + kk];
            float a2 = As[(rg * 4 + 2) * 36 + kk];
            float a3 = As[(rg * 4 + 3) * 36 + kk];
            float4 w0 = *(const float4*)(Ws + kk * 128 + cg * 8);
            float4 w1 = *(const float4*)(Ws + kk * 128 + cg * 8 + 4);
            acc[0][0] += a0 * w0.x; acc[0][1] += a0 * w0.y; acc[0][2] += a0 * w0.z; acc[0][3] += a0 * w0.w;
            acc[0][4] += a0 * w1.x; acc[0][5] += a0 * w1.y; acc[0][6] += a0 * w1.z; acc[0][7] += a0 * w1.w;
            acc[1][0] += a1 * w0.x; acc[1][1] += a1 * w0.y; acc[1][2] += a1 * w0.z; acc[1][3] += a1 * w0.w;
            acc[1][4] += a1 * w1.x; acc[1][5] += a1 * w1.y; acc[1][6] += a1 * w1.z; acc[1][7] += a1 * w1.w;
            acc[2][0] += a2 * w0.x; acc[2][1] += a2 * w0.y; acc[2][2] += a2 * w0.z; acc[2][3] += a2 * w0.w;
            acc[2][4] += a2 * w1.x; acc[2][5] += a2 * w1.y; acc[2][6] += a2 * w1.z; acc[2][7] += a2 * w1.w;
            acc[3][0] += a3 * w0.x; acc[3][1] += a3 * w0.y; acc[3][2] += a3 * w0.z; acc[3][3] += a3 * w0.w;
            acc[3][4] += a3 * w1.x; acc[3][5] += a3 * w1.y; acc[3][6] += a3 * w1.z; acc[3][7] += a3 * w1.w;
        }
    }

#pragma unroll
    for (int r = 0; r < 4; r++) {
        int row = m0 + rg * 4 + r;
        float v[8];
#pragma unroll
        for (int c = 0; c < 8; c++) {
            float x = acc[r][c];
            if (bias) x += bias[cg * 8 + c];
            if (RELU) x = fmaxf(x, 0.0f);
            v[c] = x;
        }
        float* gp = Cm + (size_t)row * 128 + cg * 8;
        *(float4*)(gp)     = make_float4(v[0], v[1], v[2], v[3]);
        *(float4*)(gp + 4) = make_float4(v[4], v[5], v[6], v[7]);
    }
}

// ---------------------------------------------------------------------------
// GCN aggregation: out[b,j] = dinv_j * sum_i (adj[b,i,j]*dinv_i*xw[b,i]) + gb
// ---------------------------------------------------------------------------
__global__ __launch_bounds__(256) void gcn_agg(
    const float* __restrict__ adj, const float* __restrict__ xw,
    const float* __restrict__ gb, float* __restrict__ outp)
{
    __shared__ float sAdj[64 * 64];
    __shared__ float sXW[64 * 128];
    __shared__ float sDinv[64];

    const int b = blockIdx.x;
    const int tid = threadIdx.x;

    const float* ga = adj + (size_t)b * 4096;
#pragma unroll
    for (int it = 0; it < 4; it++) {
        int idx = tid + it * 256;
        *(float4*)(sAdj + idx * 4) = *(const float4*)(ga + idx * 4);
    }
    const float* gx = xw + (size_t)b * 8192;
#pragma unroll
    for (int it = 0; it < 8; it++) {
        int idx = tid + it * 256;
        *(float4*)(sXW + idx * 4) = *(const float4*)(gx + idx * 4);
    }
    __syncthreads();

    if (tid < 64) {
        float d = 0.0f;
        for (int i = 0; i < 64; i++) d += sAdj[i * 64 + tid];
        sDinv[tid] = (d > 0.0f) ? rsqrtf(d) : 0.0f;
    }
    __syncthreads();

#pragma unroll
    for (int it = 0; it < 8; it++) {
        int idx = tid + it * 256;
        int i = idx >> 5;
        float s = sDinv[i];
        float4 v = *(float4*)(sXW + idx * 4);
        v.x *= s; v.y *= s; v.z *= s; v.w *= s;
        *(float4*)(sXW + idx * 4) = v;
    }
    __syncthreads();

    const int j  = tid >> 2;
    const int eb = (tid & 3) * 32;
    float acc[32];
#pragma unroll
    for (int e = 0; e < 32; e++) acc[e] = 0.0f;

    for (int i = 0; i < 64; i++) {
        float wgt = sAdj[i * 64 + j];
        const float* xp = sXW + i * 128 + eb;
#pragma unroll
        for (int e4 = 0; e4 < 8; e4++) {
            float4 v = *(const float4*)(xp + e4 * 4);
            acc[e4 * 4 + 0] += wgt * v.x;
            acc[e4 * 4 + 1] += wgt * v.y;
            acc[e4 * 4 + 2] += wgt * v.z;
            acc[e4 * 4 + 3] += wgt * v.w;
        }
    }

    const float dj = sDinv[j];
    float* go = outp + ((size_t)b * 64 + j) * 128 + eb;
#pragma unroll
    for (int e4 = 0; e4 < 8; e4++) {
        float4 v;
        v.x = acc[e4 * 4 + 0] * dj + gb[eb + e4 * 4 + 0];
        v.y = acc[e4 * 4 + 1] * dj + gb[eb + e4 * 4 + 1];
        v.z = acc[e4 * 4 + 2] * dj + gb[eb + e4 * 4 + 2];
        v.w = acc[e4 * 4 + 3] * dj + gb[eb + e4 * 4 + 3];
        *(float4*)(go + e4 * 4) = v;
    }
}

// ---------------------------------------------------------------------------
extern "C" void kernel_launch(void* const* d_in, const int* in_sizes, int n_in,
                              void* d_out, int out_size, void* d_ws, size_t ws_size,
                              hipStream_t stream)
{
    const float* states = (const float*)d_in[0];
    const float* adj    = (const float*)d_in[1];
    const float* cw0 = (const float*)d_in[2];  const float* cb0 = (const float*)d_in[3];
    const float* cw1 = (const float*)d_in[4];  const float* cb1 = (const float*)d_in[5];
    const float* cw2 = (const float*)d_in[6];  const float* cb2 = (const float*)d_in[7];
    const float* cw3 = (const float*)d_in[8];  const float* cb3 = (const float*)d_in[9];
    const float* mw0 = (const float*)d_in[10]; const float* mb0 = (const float*)d_in[11];
    const float* mw1 = (const float*)d_in[12]; const float* mb1 = (const float*)d_in[13];
    const float* mw2 = (const float*)d_in[14]; const float* mb2 = (const float*)d_in[15];
    const float* gw  = (const float*)d_in[16]; const float* gb  = (const float*)d_in[17];

    float* ws = (float*)d_ws;
    float* X0 = ws;                                   // 16384*1568 floats
    float* Bu = ws + (size_t)25690112;                // 16384*128
    float* Cu = Bu + (size_t)2097152;                 // 16384*128
    short* WB = (short*)(Cu + (size_t)2097152);       // 36864 shorts

    float* out = (float*)d_out;

    wprep<<<144, 256, 0, stream>>>(cw0, cw1, cw2, cw3, WB);
    conv_mfma<<<16384, 256, 0, stream>>>(states, WB, cb0, cb1, cb2, cb3, X0);
    gemm128<1568, true ><<<256, 256, 0, stream>>>(X0, mw0, mb0, Bu);   // H1
    gemm128<128,  true ><<<256, 256, 0, stream>>>(Bu, mw1, mb1, Cu);   // H2
    gemm128<128,  false><<<256, 256, 0, stream>>>(Cu, mw2, mb2, Bu);   // feats
    gemm128<128,  false><<<256, 256, 0, stream>>>(Bu, gw, nullptr, Cu);// xw
    gcn_agg<<<256, 256, 0, stream>>>(adj, Cu, gb, out);
}